// Round 6
// baseline (203.138 us; speedup 1.0000x reference)
//
#include <hip/hip_runtime.h>
#include <hip/hip_bf16.h>

typedef __attribute__((ext_vector_type(8))) short bf16x8;
typedef __attribute__((ext_vector_type(4))) float f32x4;
typedef __attribute__((ext_vector_type(4))) unsigned short ushort4v;

// 0.125 * log2(e): folded into Q so attention probs are exp2(QK) directly
#define QSCALE 0.1803368801111204f

__device__ __forceinline__ unsigned short f2bf(float f) {
  union { float f; unsigned int u; } x; x.f = f;
  unsigned int u = x.u;
  unsigned int r = (u + 0x7fffu + ((u >> 16) & 1u)) >> 16;
  return (unsigned short)r;
}

// pack 2 fp32 -> 1 dword of 2 bf16 (v_cvt_pk_bf16_f32 on gfx950)
__device__ __forceinline__ int bfpack2(float a, float b) {
  union { __hip_bfloat162 h; int u; } c;
  c.h = __float22bfloat162_rn(make_float2(a, b));
  return c.u;
}

// ---- fused prep: z<4 transpose+convert weights; z==4 convert x ----
__global__ __launch_bounds__(256) void prep_kernel(
    const float* __restrict__ x,
    const float* __restrict__ Wq, const float* __restrict__ Wk,
    const float* __restrict__ Wv, const float* __restrict__ Wo,
    unsigned short* __restrict__ xb,
    unsigned short* __restrict__ QKVt, unsigned short* __restrict__ Wot) {
  int z = blockIdx.z;
  if (z == 4) {  // x: 4096x1024 fp32 -> bf16
    size_t base = ((size_t)(blockIdx.y * 32 + blockIdx.x)) * 4096 + threadIdx.x * 16;
#pragma unroll
    for (int c = 0; c < 4; ++c) {
      float4 v = *(const float4*)(x + base + c * 4);
      ushort4v o = { f2bf(v.x), f2bf(v.y), f2bf(v.z), f2bf(v.w) };
      *(ushort4v*)(xb + base + c * 4) = o;
    }
    return;
  }
  __shared__ float t[32][33];
  const float* src;
  unsigned short* dst;
  int C, rowoff;
  if (z == 0)      { src = Wq; dst = QKVt; C = 1024; rowoff = 0; }
  else if (z == 1) { src = Wk; dst = QKVt; C = 64;   rowoff = 1024; }
  else if (z == 2) { src = Wv; dst = QKVt; C = 64;   rowoff = 1088; }
  else             { src = Wo; dst = Wot;  C = 1024; rowoff = 0; }
  int c0 = blockIdx.x * 32, r0 = blockIdx.y * 32;
  if (c0 >= C) return;
  int tx = threadIdx.x & 31, ty = threadIdx.x >> 5;
#pragma unroll
  for (int i = 0; i < 32; i += 8)
    t[ty + i][tx] = src[(size_t)(r0 + ty + i) * C + c0 + tx];
  __syncthreads();
#pragma unroll
  for (int i = 0; i < 32; i += 8)
    dst[(size_t)(rowoff + c0 + ty + i) * 1024 + r0 + tx] = f2bf(t[tx][ty + i]);
}

// ------- bf16 MFMA GEMM: C[M][N] = A[M][K] @ Bt[N][K]^T + bias -------
// 128x64 tile (more blocks for grid-starved shapes), BK=32, reg-prefetch +
// LDS double-buffer, ONE barrier/iter. 4 waves, each 64x32 (4x2 mfma16).
template <typename OutT, bool QKVMODE>
__global__ __launch_bounds__(256) void gemm_bf16_kernel(
    const unsigned short* __restrict__ A, const unsigned short* __restrict__ Bt,
    const float* __restrict__ b0, const float* __restrict__ b1,
    const float* __restrict__ b2, OutT* __restrict__ C,
    unsigned short* __restrict__ Vt, int M, int N, int K) {
  constexpr int LS = 40;
  __shared__ unsigned short As[2][128 * LS];
  __shared__ unsigned short Bs[2][64 * LS];
  int tid = threadIdx.x;
  int wid = tid >> 6, lane = tid & 63;
  int l15 = lane & 15, quad = lane >> 4;
  int m0 = blockIdx.x * 128, n0 = blockIdx.y * 64;
  int mw = (wid >> 1) * 64, nw = (wid & 1) * 32;
  f32x4 acc[4][2];
#pragma unroll
  for (int i = 0; i < 4; i++)
#pragma unroll
    for (int j = 0; j < 2; j++)
#pragma unroll
      for (int e = 0; e < 4; ++e) acc[i][j][e] = 0.f;

  int arow = tid >> 2, akc = (tid & 3) * 8;
  const unsigned short* Ag = A + (size_t)(m0 + arow) * K + akc;
  const unsigned short* Bg = Bt + (size_t)(n0 + (tid >> 2)) * K + akc;
  bf16x8 ar0 = *(const bf16x8*)(Ag);
  bf16x8 ar1 = *(const bf16x8*)(Ag + (size_t)64 * K);
  bf16x8 br0 = *(const bf16x8*)(Bg);

  for (int k0 = 0; k0 < K; k0 += 32) {
    unsigned short* Asb = As[(k0 >> 5) & 1];
    unsigned short* Bsb = Bs[(k0 >> 5) & 1];
    *(bf16x8*)(Asb + arow * LS + akc) = ar0;
    *(bf16x8*)(Asb + (arow + 64) * LS + akc) = ar1;
    *(bf16x8*)(Bsb + arow * LS + akc) = br0;  // arow==tid>>2 covers 64 rows x2 passes? no: rows 0..63 use first 256 chunks
    __syncthreads();
    if (k0 + 32 < K) {
      ar0 = *(const bf16x8*)(Ag + k0 + 32);
      ar1 = *(const bf16x8*)(Ag + (size_t)64 * K + k0 + 32);
      br0 = *(const bf16x8*)(Bg + k0 + 32);
    }
    bf16x8 af[4], bfr[2];
#pragma unroll
    for (int t = 0; t < 4; ++t)
      af[t] = *(const bf16x8*)(Asb + (mw + t * 16 + l15) * LS + quad * 8);
#pragma unroll
    for (int t = 0; t < 2; ++t)
      bfr[t] = *(const bf16x8*)(Bsb + (nw + t * 16 + l15) * LS + quad * 8);
#pragma unroll
    for (int mt = 0; mt < 4; ++mt)
#pragma unroll
      for (int nt = 0; nt < 2; ++nt)
        acc[mt][nt] = __builtin_amdgcn_mfma_f32_16x16x32_bf16(
            af[mt], bfr[nt], acc[mt][nt], 0, 0, 0);
  }
#pragma unroll
  for (int mt = 0; mt < 4; ++mt)
#pragma unroll
    for (int nt = 0; nt < 2; ++nt) {
      int col = n0 + nw + nt * 16 + l15;
      float bias, cs;
      if constexpr (QKVMODE) {
        bias = (col < 1024) ? b0[col] : ((col < 1088) ? b1[col - 1024] : b2[col - 1088]);
        cs = (col < 1024) ? QSCALE : 1.0f;
      } else {
        bias = b0[col];
        cs = 1.0f;
      }
#pragma unroll
      for (int r = 0; r < 4; ++r) {
        int row = m0 + mw + mt * 16 + quad * 4 + r;
        float v = (acc[mt][nt][r] + bias) * cs;
        if constexpr (sizeof(OutT) == 2)
          C[(size_t)row * N + col] = f2bf(v);
        else
          C[(size_t)row * N + col] = v;
        if constexpr (QKVMODE) {
          if (col >= 1088)  // scatter V^T for flash: Vt[b*64+d][s]
            Vt[((size_t)(row >> 11) * 64 + (col - 1088)) * 2048 + (row & 2047)] =
                f2bf(v);
        }
      }
    }
}

// ---------------- flash attention (MQA, 16-query waves for occupancy) -------
// Grid (S/64, H, B) = 1024 blocks, 4 waves; wave w -> 16 queries. 16x16x32
// MFMA, S^T = K.Q^T form (P lane-resident, col=q). P^T B-operand assembled
// via ds_bpermute gather (no P LDS buffer -> 36.9KB LDS -> 4 blocks/CU).
__global__ __launch_bounds__(256, 4) void flash_attn_kernel(
    const unsigned short* __restrict__ QKV,  // [B*S][1152] bf16: Q|K|V
    const unsigned short* __restrict__ Vt,   // [B][64][2048] bf16
    unsigned short* __restrict__ AO) {       // [B*S][1024] bf16
  constexpr int S = 2048, LDQ = 1152;
  constexpr int PK = 72;
  __shared__ unsigned short Ks[2][64 * PK];
  __shared__ unsigned short Vs[2][64 * PK];
  int tid = threadIdx.x;
  int wid = tid >> 6, lane = tid & 63;
  int l15 = lane & 15, quad = lane >> 4;
  int q0 = blockIdx.x * 64, h = blockIdx.y, b = blockIdx.z;

  // Q B-frags: [n=q=l15][k(d) = c*32 + quad*8 + j]
  const unsigned short* Qb =
      QKV + (size_t)(b * S + q0 + wid * 16 + l15) * LDQ + h * 64 + quad * 8;
  bf16x8 qf[2];
  qf[0] = *(const bf16x8*)(Qb);
  qf[1] = *(const bf16x8*)(Qb + 32);

  int srow = tid >> 3, skc = (tid & 7) * 8;
  const unsigned short* Kg = QKV + ((size_t)(b * S + srow) * LDQ + 1024 + skc);
  const unsigned short* Vg = Vt + ((size_t)(b * 64 + srow) * 2048 + skc);

  // bpermute source lanes (loop-invariant): quad_s = (2*quad + (d2>>1)) & 3
  int addrA = ((((quad << 1)) & 3) * 16 + l15) << 2;      // d2 in {0,1}
  int addrB = ((((quad << 1) + 1) & 3) * 16 + l15) << 2;  // d2 in {2,3}
  bool hi = quad >= 2;  // selects held[2c+1] vs held[2c]

  f32x4 oacc[4];
#pragma unroll
  for (int i = 0; i < 4; ++i)
#pragma unroll
    for (int e = 0; e < 4; ++e) oacc[i][e] = 0.f;
  float rsacc = 0.f;

  bf16x8 kr0 = *(const bf16x8*)(Kg);
  bf16x8 kr1 = *(const bf16x8*)(Kg + (size_t)32 * LDQ);
  bf16x8 vr0 = *(const bf16x8*)(Vg);
  bf16x8 vr1 = *(const bf16x8*)(Vg + (size_t)32 * 2048);

  for (int kb = 0; kb < S; kb += 64) {
    unsigned short* Ksb = Ks[(kb >> 6) & 1];
    unsigned short* Vsb = Vs[(kb >> 6) & 1];
    *(bf16x8*)(Ksb + srow * PK + skc) = kr0;
    *(bf16x8*)(Ksb + (srow + 32) * PK + skc) = kr1;
    *(bf16x8*)(Vsb + srow * PK + skc) = vr0;
    *(bf16x8*)(Vsb + (srow + 32) * PK + skc) = vr1;
    __syncthreads();
    if (kb + 64 < S) {  // reg prefetch, in flight across the whole tile
      kr0 = *(const bf16x8*)(Kg + (size_t)(kb + 64) * LDQ);
      kr1 = *(const bf16x8*)(Kg + (size_t)(kb + 96) * LDQ);
      vr0 = *(const bf16x8*)(Vg + kb + 64);
      vr1 = *(const bf16x8*)(Vg + (size_t)32 * 2048 + kb + 64);
    }

    // S^T = K.Q^T : C col=q=l15, row=key = mt*16 + quad*4 + r
    f32x4 sacc[4];
#pragma unroll
    for (int mt = 0; mt < 4; ++mt)
#pragma unroll
      for (int e = 0; e < 4; ++e) sacc[mt][e] = 0.f;
#pragma unroll
    for (int mt = 0; mt < 4; ++mt)
#pragma unroll
      for (int c = 0; c < 2; ++c) {
        bf16x8 kf =
            *(const bf16x8*)(Ksb + (mt * 16 + l15) * PK + c * 32 + quad * 8);
        sacc[mt] = __builtin_amdgcn_mfma_f32_16x16x32_bf16(kf, qf[c], sacc[mt], 0, 0, 0);
      }

    // p = exp2(s); pack key-pairs into dwords. held[mt][pr]: keys mt*16+quad*4+2pr,+1
    int held[4][2];
#pragma unroll
    for (int mt = 0; mt < 4; ++mt) {
      float p0 = __builtin_amdgcn_exp2f(sacc[mt][0]);
      float p1 = __builtin_amdgcn_exp2f(sacc[mt][1]);
      float p2 = __builtin_amdgcn_exp2f(sacc[mt][2]);
      float p3 = __builtin_amdgcn_exp2f(sacc[mt][3]);
      rsacc += (p0 + p1) + (p2 + p3);
      held[mt][0] = bfpack2(p0, p1);
      held[mt][1] = bfpack2(p2, p3);
    }

    // Assemble P^T B-frags: pfr[c] dword d2 = keys c*32+quad*8+2d2,+1
    // source reg held[2c + (quad>>1)][d2&1] at lane (2*quad + (d2>>1))&3 * 16 + l15
    bf16x8 pfr[2];
#pragma unroll
    for (int c = 0; c < 2; ++c) {
      union { bf16x8 v; int u[4]; } fr;
#pragma unroll
      for (int d2 = 0; d2 < 4; ++d2) {
        int a = (d2 & 2) ? addrB : addrA;
        int t0 = __builtin_amdgcn_ds_bpermute(a, held[2 * c][d2 & 1]);
        int t1 = __builtin_amdgcn_ds_bpermute(a, held[2 * c + 1][d2 & 1]);
        fr.u[d2] = hi ? t1 : t0;
      }
      pfr[c] = fr.v;
    }

    // O^T += V^T . P^T : A = V^T frag [m=d][k=key]
#pragma unroll
    for (int mt2 = 0; mt2 < 4; ++mt2)
#pragma unroll
      for (int c = 0; c < 2; ++c) {
        bf16x8 vf =
            *(const bf16x8*)(Vsb + (mt2 * 16 + l15) * PK + c * 32 + quad * 8);
        oacc[mt2] = __builtin_amdgcn_mfma_f32_16x16x32_bf16(vf, pfr[c], oacc[mt2], 0, 0, 0);
      }
  }

  // row sum for q=l15: reduce partials across the 4 quads
  float s = rsacc;
  s += __shfl_xor(s, 16);
  s += __shfl_xor(s, 32);
  float inv = 1.0f / s;

  // O^T: col=q=l15, row=d = mt2*16 + quad*4 + r -> ushort4 stores
  unsigned short* Ob = AO + (size_t)(b * S + q0 + wid * 16 + l15) * 1024 + h * 64;
#pragma unroll
  for (int mt2 = 0; mt2 < 4; ++mt2) {
    union { ushort4v s4; int u[2]; } w;
    w.u[0] = bfpack2(oacc[mt2][0] * inv, oacc[mt2][1] * inv);
    w.u[1] = bfpack2(oacc[mt2][2] * inv, oacc[mt2][3] * inv);
    *(ushort4v*)(Ob + mt2 * 16 + quad * 4) = w.s4;
  }
}

extern "C" void kernel_launch(void* const* d_in, const int* in_sizes, int n_in,
                              void* d_out, int out_size, void* d_ws, size_t ws_size,
                              hipStream_t stream) {
  const float* x  = (const float*)d_in[0];
  const float* Wq = (const float*)d_in[1];
  const float* bq = (const float*)d_in[2];
  const float* Wk = (const float*)d_in[3];
  const float* bk = (const float*)d_in[4];
  const float* Wv = (const float*)d_in[5];
  const float* bv = (const float*)d_in[6];
  const float* Wo = (const float*)d_in[7];
  const float* bo = (const float*)d_in[8];
  float* out = (float*)d_out;

  constexpr int B = 2, S = 2048, D = 1024, Dk = 64, H = 16;
  constexpr int M = B * S;          // 4096
  constexpr int NQKV = D + 2 * Dk;  // 1152

  char* ws = (char*)d_ws;
  unsigned short* xb   = (unsigned short*)ws; ws += (size_t)M * D * 2;
  unsigned short* QKVt = (unsigned short*)ws; ws += (size_t)NQKV * D * 2;
  unsigned short* Wot  = (unsigned short*)ws; ws += (size_t)D * D * 2;
  unsigned short* QKV  = (unsigned short*)ws; ws += (size_t)M * NQKV * 2;
  unsigned short* Vtb  = (unsigned short*)ws; ws += (size_t)B * Dk * S * 2;
  unsigned short* AO   = (unsigned short*)ws; ws += (size_t)M * D * 2;

  // 1. one prep kernel: convert x (z=4) + transpose/convert 4 weights (z=0..3)
  prep_kernel<<<dim3(32, 32, 5), 256, 0, stream>>>(x, Wq, Wk, Wv, Wo, xb, QKVt, Wot);

  // 2. fused QKV projection (128x64 tiles -> 576 blocks); V^T scatter in epilogue
  gemm_bf16_kernel<unsigned short, true><<<dim3(M / 128, NQKV / 64), 256, 0, stream>>>(
      xb, QKVt, bq, bk, bv, QKV, Vtb, M, NQKV, D);

  // 3. attention (1024 blocks, 4 blocks/CU)
  flash_attn_kernel<<<dim3(S / 64, H, B), 256, 0, stream>>>(QKV, Vtb, AO);

  // 4. output projection (fp32 out, 512 blocks)
  gemm_bf16_kernel<float, false><<<dim3(M / 128, D / 64), 256, 0, stream>>>(
      AO, Wot, bo, nullptr, nullptr, out, nullptr, M, D, D);
}

// Round 7
// 201.149 us; speedup vs baseline: 1.0099x; 1.0099x over previous
//
#include <hip/hip_runtime.h>
#include <hip/hip_bf16.h>

typedef __attribute__((ext_vector_type(8))) short bf16x8;
typedef __attribute__((ext_vector_type(4))) float f32x4;
typedef __attribute__((ext_vector_type(16))) float f32x16;
typedef __attribute__((ext_vector_type(4))) unsigned short ushort4v;

// 0.125 * log2(e): folded into Q so attention probs are exp2(QK) directly
#define QSCALE 0.1803368801111204f

__device__ __forceinline__ unsigned short f2bf(float f) {
  union { float f; unsigned int u; } x; x.f = f;
  unsigned int u = x.u;
  unsigned int r = (u + 0x7fffu + ((u >> 16) & 1u)) >> 16;
  return (unsigned short)r;
}

// pack 2 fp32 -> 1 dword of 2 bf16 (v_cvt_pk_bf16_f32 on gfx950)
__device__ __forceinline__ int bfpack2(float a, float b) {
  union { __hip_bfloat162 h; int u; } c;
  c.h = __float22bfloat162_rn(make_float2(a, b));
  return c.u;
}

__device__ __forceinline__ bf16x8 pack8(float4 a, float4 b) {
  union { bf16x8 v; int u[4]; } c;
  c.u[0] = bfpack2(a.x, a.y);
  c.u[1] = bfpack2(a.z, a.w);
  c.u[2] = bfpack2(b.x, b.y);
  c.u[3] = bfpack2(b.z, b.w);
  return c.v;
}

// ---- prep: transpose+convert 4 weights (z-indexed) ----
__global__ __launch_bounds__(256) void prep_kernel(
    const float* __restrict__ Wq, const float* __restrict__ Wk,
    const float* __restrict__ Wv, const float* __restrict__ Wo,
    unsigned short* __restrict__ QKVt, unsigned short* __restrict__ Wot) {
  __shared__ float t[32][33];
  int z = blockIdx.z;
  const float* src;
  unsigned short* dst;
  int C, rowoff;
  if (z == 0)      { src = Wq; dst = QKVt; C = 1024; rowoff = 0; }
  else if (z == 1) { src = Wk; dst = QKVt; C = 64;   rowoff = 1024; }
  else if (z == 2) { src = Wv; dst = QKVt; C = 64;   rowoff = 1088; }
  else             { src = Wo; dst = Wot;  C = 1024; rowoff = 0; }
  int c0 = blockIdx.x * 32, r0 = blockIdx.y * 32;
  if (c0 >= C) return;
  int tx = threadIdx.x & 31, ty = threadIdx.x >> 5;
#pragma unroll
  for (int i = 0; i < 32; i += 8)
    t[ty + i][tx] = src[(size_t)(r0 + ty + i) * C + c0 + tx];
  __syncthreads();
#pragma unroll
  for (int i = 0; i < 32; i += 8)
    dst[(size_t)(rowoff + c0 + ty + i) * 1024 + r0 + tx] = f2bf(t[tx][ty + i]);
}

// ------- MFMA GEMM: C[M][N] = A[M][K] @ Bt[N][K]^T + bias -------
// 128x64 tile, BK=32, reg-prefetch + LDS double-buffer, ONE barrier/iter.
// AFP32: A is fp32, converted to bf16 during staging (x consumed directly).
// QKVMODE: per-column bias select + QSCALE on Q cols; V cols scatter V^T.
template <bool AFP32, typename OutT, bool QKVMODE>
__global__ __launch_bounds__(256) void gemm_kernel(
    const void* __restrict__ Av, const unsigned short* __restrict__ Bt,
    const float* __restrict__ b0, const float* __restrict__ b1,
    const float* __restrict__ b2, OutT* __restrict__ C,
    unsigned short* __restrict__ Vt, int M, int N, int K) {
  constexpr int LS = 40;
  __shared__ unsigned short As[2][128 * LS];
  __shared__ unsigned short Bs[2][64 * LS];
  int tid = threadIdx.x;
  int wid = tid >> 6, lane = tid & 63;
  int l15 = lane & 15, quad = lane >> 4;
  int m0 = blockIdx.x * 128, n0 = blockIdx.y * 64;
  int mw = (wid >> 1) * 64, nw = (wid & 1) * 32;
  f32x4 acc[4][2];
#pragma unroll
  for (int i = 0; i < 4; i++)
#pragma unroll
    for (int j = 0; j < 2; j++)
#pragma unroll
      for (int e = 0; e < 4; ++e) acc[i][j][e] = 0.f;

  int arow = tid >> 2, akc = (tid & 3) * 8;
  const unsigned short* Ag = nullptr;
  const float* Agf = nullptr;
  bf16x8 ar0, ar1;
  float4 f0a, f0b, f1a, f1b;
  if constexpr (AFP32) {
    Agf = (const float*)Av + (size_t)(m0 + arow) * K + akc;
    f0a = *(const float4*)(Agf);
    f0b = *(const float4*)(Agf + 4);
    f1a = *(const float4*)(Agf + (size_t)64 * K);
    f1b = *(const float4*)(Agf + (size_t)64 * K + 4);
  } else {
    Ag = (const unsigned short*)Av + (size_t)(m0 + arow) * K + akc;
    ar0 = *(const bf16x8*)(Ag);
    ar1 = *(const bf16x8*)(Ag + (size_t)64 * K);
  }
  const unsigned short* Bg = Bt + (size_t)(n0 + arow) * K + akc;
  bf16x8 br0 = *(const bf16x8*)(Bg);

  for (int k0 = 0; k0 < K; k0 += 32) {
    unsigned short* Asb = As[(k0 >> 5) & 1];
    unsigned short* Bsb = Bs[(k0 >> 5) & 1];
    if constexpr (AFP32) {
      *(bf16x8*)(Asb + arow * LS + akc) = pack8(f0a, f0b);
      *(bf16x8*)(Asb + (arow + 64) * LS + akc) = pack8(f1a, f1b);
    } else {
      *(bf16x8*)(Asb + arow * LS + akc) = ar0;
      *(bf16x8*)(Asb + (arow + 64) * LS + akc) = ar1;
    }
    *(bf16x8*)(Bsb + arow * LS + akc) = br0;
    __syncthreads();
    if (k0 + 32 < K) {  // prefetch next k-tile; in flight across this tile
      if constexpr (AFP32) {
        f0a = *(const float4*)(Agf + k0 + 32);
        f0b = *(const float4*)(Agf + k0 + 36);
        f1a = *(const float4*)(Agf + (size_t)64 * K + k0 + 32);
        f1b = *(const float4*)(Agf + (size_t)64 * K + k0 + 36);
      } else {
        ar0 = *(const bf16x8*)(Ag + k0 + 32);
        ar1 = *(const bf16x8*)(Ag + (size_t)64 * K + k0 + 32);
      }
      br0 = *(const bf16x8*)(Bg + k0 + 32);
    }
    bf16x8 af[4], bfr[2];
#pragma unroll
    for (int t = 0; t < 4; ++t)
      af[t] = *(const bf16x8*)(Asb + (mw + t * 16 + l15) * LS + quad * 8);
#pragma unroll
    for (int t = 0; t < 2; ++t)
      bfr[t] = *(const bf16x8*)(Bsb + (nw + t * 16 + l15) * LS + quad * 8);
#pragma unroll
    for (int mt = 0; mt < 4; ++mt)
#pragma unroll
      for (int nt = 0; nt < 2; ++nt)
        acc[mt][nt] = __builtin_amdgcn_mfma_f32_16x16x32_bf16(
            af[mt], bfr[nt], acc[mt][nt], 0, 0, 0);
  }
#pragma unroll
  for (int mt = 0; mt < 4; ++mt)
#pragma unroll
    for (int nt = 0; nt < 2; ++nt) {
      int col = n0 + nw + nt * 16 + l15;
      float bias, cs;
      if constexpr (QKVMODE) {
        bias = (col < 1024) ? b0[col] : ((col < 1088) ? b1[col - 1024] : b2[col - 1088]);
        cs = (col < 1024) ? QSCALE : 1.0f;
      } else {
        bias = b0[col];
        cs = 1.0f;
      }
#pragma unroll
      for (int r = 0; r < 4; ++r) {
        int row = m0 + mw + mt * 16 + quad * 4 + r;
        float v = (acc[mt][nt][r] + bias) * cs;
        if constexpr (sizeof(OutT) == 2)
          C[(size_t)row * N + col] = f2bf(v);
        else
          C[(size_t)row * N + col] = v;
        if constexpr (QKVMODE) {
          if (col >= 1088)  // scatter V^T for flash: Vt[b*64+d][s]
            Vt[((size_t)(row >> 11) * 64 + (col - 1088)) * 2048 + (row & 2047)] =
                f2bf(v);
        }
      }
    }
}

// ---------------- flash attention (MQA, S^T form, packed-P LDS) ----------------
// Grid (S/128, H, B) = 512 blocks, 256 thr = 4 waves; wave -> 32 queries.
// 32x32x16 MFMA; S^T = K.Q^T keeps P lane-resident with col=q; adjacent C
// regs are ADJACENT KEYS -> P^T written with packed ds_write_b64 (PP=68:
// 2-way bank alias on writes = free, reads conflict-free, 8B aligned).
// Double-buffered K/V, single barrier/tile, register prefetch.
__global__ __launch_bounds__(256) void flash_attn_kernel(
    const unsigned short* __restrict__ QKV,  // [B*S][1152] bf16: Q|K|V
    const unsigned short* __restrict__ Vt,   // [B][64][2048] bf16
    unsigned short* __restrict__ AO) {       // [B*S][1024] bf16
  constexpr int S = 2048, LDQ = 1152;
  constexpr int PK = 72, PP = 68;
  __shared__ unsigned short Ks[2][64 * PK];
  __shared__ unsigned short Vs[2][64 * PK];
  __shared__ unsigned short Pt[4][32 * PP];  // per-wave P^T [q][key]
  int tid = threadIdx.x;
  int wid = tid >> 6, lane = tid & 63;
  int l31 = lane & 31, half = lane >> 5;
  int q0 = blockIdx.x * 128, h = blockIdx.y, b = blockIdx.z;

  // Q B-frags: n=q=l31, k(d) = s4*16 + half*8 + j
  const unsigned short* Qb =
      QKV + (size_t)(b * S + q0 + wid * 32 + l31) * LDQ + h * 64 + half * 8;
  bf16x8 qf[4];
#pragma unroll
  for (int f = 0; f < 4; ++f) qf[f] = *(const bf16x8*)(Qb + f * 16);

  int srow = tid >> 3, skc = (tid & 7) * 8;
  const unsigned short* Kg = QKV + ((size_t)(b * S + srow) * LDQ + 1024 + skc);
  const unsigned short* Vg = Vt + ((size_t)(b * 64 + srow) * 2048 + skc);
  unsigned short* Ptw = Pt[wid] + l31 * PP;  // row q = l31

  f32x16 oacc[2];
#pragma unroll
  for (int r = 0; r < 16; ++r) { oacc[0][r] = 0.f; oacc[1][r] = 0.f; }
  float rsacc = 0.f;

  bf16x8 kr0 = *(const bf16x8*)(Kg);
  bf16x8 kr1 = *(const bf16x8*)(Kg + (size_t)32 * LDQ);
  bf16x8 vr0 = *(const bf16x8*)(Vg);
  bf16x8 vr1 = *(const bf16x8*)(Vg + (size_t)32 * 2048);

  for (int kb = 0; kb < S; kb += 64) {
    unsigned short* Ksb = Ks[(kb >> 6) & 1];
    unsigned short* Vsb = Vs[(kb >> 6) & 1];
    *(bf16x8*)(Ksb + srow * PK + skc) = kr0;
    *(bf16x8*)(Ksb + (srow + 32) * PK + skc) = kr1;
    *(bf16x8*)(Vsb + srow * PK + skc) = vr0;
    *(bf16x8*)(Vsb + (srow + 32) * PK + skc) = vr1;
    __syncthreads();
    if (kb + 64 < S) {  // reg prefetch; in flight across full tile compute
      kr0 = *(const bf16x8*)(Kg + (size_t)(kb + 64) * LDQ);
      kr1 = *(const bf16x8*)(Kg + (size_t)(kb + 96) * LDQ);
      vr0 = *(const bf16x8*)(Vg + kb + 64);
      vr1 = *(const bf16x8*)(Vg + (size_t)32 * 2048 + kb + 64);
    }

    // S^T = K.Q^T per 32-key chunk; p = exp2(s); pack 4 adjacent keys -> b64
#pragma unroll
    for (int mt2 = 0; mt2 < 2; ++mt2) {
      f32x16 sacc;
#pragma unroll
      for (int i = 0; i < 16; ++i) sacc[i] = 0.f;
#pragma unroll
      for (int s4 = 0; s4 < 4; ++s4) {
        bf16x8 kf =
            *(const bf16x8*)(Ksb + (mt2 * 32 + l31) * PK + s4 * 16 + half * 8);
        sacc = __builtin_amdgcn_mfma_f32_32x32x16_bf16(kf, qf[s4], sacc, 0, 0, 0);
      }
      // reg r -> key mt2*32 + (r&3) + 8*(r>>2) + 4*half; col q = l31
#pragma unroll
      for (int g = 0; g < 4; ++g) {
        float p0 = __builtin_amdgcn_exp2f(sacc[4 * g + 0]);
        float p1 = __builtin_amdgcn_exp2f(sacc[4 * g + 1]);
        float p2 = __builtin_amdgcn_exp2f(sacc[4 * g + 2]);
        float p3 = __builtin_amdgcn_exp2f(sacc[4 * g + 3]);
        rsacc += (p0 + p1) + (p2 + p3);
        int2 w;
        w.x = bfpack2(p0, p1);
        w.y = bfpack2(p2, p3);
        *(int2*)(Ptw + mt2 * 32 + 8 * g + 4 * half) = w;
      }
    }

    // O^T += V^T . P^T : B-frags of P^T read back (wave-private, no barrier)
    bf16x8 pfb[4];
#pragma unroll
    for (int s = 0; s < 4; ++s)
      pfb[s] = *(const bf16x8*)(Ptw + s * 16 + half * 8);
#pragma unroll
    for (int d2 = 0; d2 < 2; ++d2)
#pragma unroll
      for (int s = 0; s < 4; ++s) {
        bf16x8 vf =
            *(const bf16x8*)(Vsb + (d2 * 32 + l31) * PK + s * 16 + half * 8);
        oacc[d2] = __builtin_amdgcn_mfma_f32_32x32x16_bf16(vf, pfb[s], oacc[d2], 0, 0, 0);
      }
  }

  // row sum for query l31: own partial + other half's partial
  float inv = 1.0f / (rsacc + __shfl_xor(rsacc, 32));

  // O^T: col=q=l31, row=d = d2*32 + (r&3)+8*(r>>2)+4*half -> packed stores
  unsigned short* Ob = AO + (size_t)(b * S + q0 + wid * 32 + l31) * 1024 + h * 64;
#pragma unroll
  for (int d2 = 0; d2 < 2; ++d2)
#pragma unroll
    for (int g = 0; g < 4; ++g) {
      union { ushort4v s4; int u[2]; } w;
      w.u[0] = bfpack2(oacc[d2][4 * g + 0] * inv, oacc[d2][4 * g + 1] * inv);
      w.u[1] = bfpack2(oacc[d2][4 * g + 2] * inv, oacc[d2][4 * g + 3] * inv);
      *(ushort4v*)(Ob + d2 * 32 + 8 * g + 4 * half) = w.s4;
    }
}

extern "C" void kernel_launch(void* const* d_in, const int* in_sizes, int n_in,
                              void* d_out, int out_size, void* d_ws, size_t ws_size,
                              hipStream_t stream) {
  const float* x  = (const float*)d_in[0];
  const float* Wq = (const float*)d_in[1];
  const float* bq = (const float*)d_in[2];
  const float* Wk = (const float*)d_in[3];
  const float* bk = (const float*)d_in[4];
  const float* Wv = (const float*)d_in[5];
  const float* bv = (const float*)d_in[6];
  const float* Wo = (const float*)d_in[7];
  const float* bo = (const float*)d_in[8];
  float* out = (float*)d_out;

  constexpr int B = 2, S = 2048, D = 1024, Dk = 64, H = 16;
  constexpr int M = B * S;          // 4096
  constexpr int NQKV = D + 2 * Dk;  // 1152

  char* ws = (char*)d_ws;
  unsigned short* QKVt = (unsigned short*)ws; ws += (size_t)NQKV * D * 2;
  unsigned short* Wot  = (unsigned short*)ws; ws += (size_t)D * D * 2;
  unsigned short* QKV  = (unsigned short*)ws; ws += (size_t)M * NQKV * 2;
  unsigned short* Vtb  = (unsigned short*)ws; ws += (size_t)B * Dk * S * 2;
  unsigned short* AO   = (unsigned short*)ws; ws += (size_t)M * D * 2;

  // 1. transpose/convert weights
  prep_kernel<<<dim3(32, 32, 4), 256, 0, stream>>>(Wq, Wk, Wv, Wo, QKVt, Wot);

  // 2. fused QKV projection from fp32 x directly (convert in staging);
  //    epilogue scatters V^T and pre-scales Q by 0.125*log2e
  gemm_kernel<true, unsigned short, true><<<dim3(M / 128, NQKV / 64), 256, 0, stream>>>(
      x, QKVt, bq, bk, bv, QKV, Vtb, M, NQKV, D);

  // 3. attention
  flash_attn_kernel<<<dim3(S / 128, H, B), 256, 0, stream>>>(QKV, Vtb, AO);

  // 4. output projection (fp32 out)
  gemm_kernel<false, float, false><<<dim3(M / 128, D / 64), 256, 0, stream>>>(
      AO, Wot, bo, nullptr, nullptr, out, nullptr, M, D, D);
}

// Round 8
// 195.791 us; speedup vs baseline: 1.0375x; 1.0274x over previous
//
#include <hip/hip_runtime.h>
#include <hip/hip_bf16.h>

typedef __attribute__((ext_vector_type(8))) short bf16x8;
typedef __attribute__((ext_vector_type(4))) float f32x4;
typedef __attribute__((ext_vector_type(16))) float f32x16;
typedef __attribute__((ext_vector_type(4))) unsigned short ushort4v;

// 0.125 * log2(e): folded into Q so attention probs are exp2(QK) directly
#define QSCALE 0.1803368801111204f

__device__ __forceinline__ unsigned short f2bf(float f) {
  union { float f; unsigned int u; } x; x.f = f;
  unsigned int u = x.u;
  unsigned int r = (u + 0x7fffu + ((u >> 16) & 1u)) >> 16;
  return (unsigned short)r;
}

// ---- fused prep: z<4 transpose+convert weights; z==4 convert x ----
__global__ __launch_bounds__(256) void prep_kernel(
    const float* __restrict__ x,
    const float* __restrict__ Wq, const float* __restrict__ Wk,
    const float* __restrict__ Wv, const float* __restrict__ Wo,
    unsigned short* __restrict__ xb,
    unsigned short* __restrict__ QKVt, unsigned short* __restrict__ Wot) {
  int z = blockIdx.z;
  if (z == 4) {  // x: 4096x1024 fp32 -> bf16
    size_t base = ((size_t)(blockIdx.y * 32 + blockIdx.x)) * 4096 + threadIdx.x * 16;
#pragma unroll
    for (int c = 0; c < 4; ++c) {
      float4 v = *(const float4*)(x + base + c * 4);
      ushort4v o = { f2bf(v.x), f2bf(v.y), f2bf(v.z), f2bf(v.w) };
      *(ushort4v*)(xb + base + c * 4) = o;
    }
    return;
  }
  __shared__ float t[32][33];
  const float* src;
  unsigned short* dst;
  int C, rowoff;
  if (z == 0)      { src = Wq; dst = QKVt; C = 1024; rowoff = 0; }
  else if (z == 1) { src = Wk; dst = QKVt; C = 64;   rowoff = 1024; }
  else if (z == 2) { src = Wv; dst = QKVt; C = 64;   rowoff = 1088; }
  else             { src = Wo; dst = Wot;  C = 1024; rowoff = 0; }
  int c0 = blockIdx.x * 32, r0 = blockIdx.y * 32;
  if (c0 >= C) return;
  int tx = threadIdx.x & 31, ty = threadIdx.x >> 5;
#pragma unroll
  for (int i = 0; i < 32; i += 8)
    t[ty + i][tx] = src[(size_t)(r0 + ty + i) * C + c0 + tx];
  __syncthreads();
#pragma unroll
  for (int i = 0; i < 32; i += 8)
    dst[(size_t)(rowoff + c0 + ty + i) * 1024 + r0 + tx] = f2bf(t[tx][ty + i]);
}

// ------- bf16 MFMA GEMM: C[M][N] = A[M][K] @ Bt[N][K]^T + bias -------
// 128x128 tile, BK=32, reg-prefetch + LDS double-buffer, ONE barrier/iter.
// QKVMODE: per-column bias select + QSCALE on Q cols; V cols scatter V^T.
template <typename OutT, bool QKVMODE>
__global__ __launch_bounds__(256) void gemm_bf16_kernel(
    const unsigned short* __restrict__ A, const unsigned short* __restrict__ Bt,
    const float* __restrict__ b0, const float* __restrict__ b1,
    const float* __restrict__ b2, OutT* __restrict__ C,
    unsigned short* __restrict__ Vt, int M, int N, int K) {
  constexpr int LS = 40;
  __shared__ unsigned short As[2][128 * LS];
  __shared__ unsigned short Bs[2][128 * LS];
  int tid = threadIdx.x;
  int wid = tid >> 6, lane = tid & 63;
  int l15 = lane & 15, quad = lane >> 4;
  int m0 = blockIdx.x * 128, n0 = blockIdx.y * 128;
  int mw = (wid >> 1) * 64, nw = (wid & 1) * 64;
  f32x4 acc[4][4];
#pragma unroll
  for (int i = 0; i < 4; i++)
#pragma unroll
    for (int j = 0; j < 4; j++)
#pragma unroll
      for (int e = 0; e < 4; ++e) acc[i][j][e] = 0.f;

  int arow = tid >> 2, akc = (tid & 3) * 8;
  const unsigned short* Ag = A + (size_t)(m0 + arow) * K + akc;
  const unsigned short* Bg = Bt + (size_t)(n0 + arow) * K + akc;
  bf16x8 ar0 = *(const bf16x8*)(Ag);
  bf16x8 ar1 = *(const bf16x8*)(Ag + (size_t)64 * K);
  bf16x8 br0 = *(const bf16x8*)(Bg);
  bf16x8 br1 = *(const bf16x8*)(Bg + (size_t)64 * K);

  for (int k0 = 0; k0 < K; k0 += 32) {
    unsigned short* Asb = As[(k0 >> 5) & 1];
    unsigned short* Bsb = Bs[(k0 >> 5) & 1];
    *(bf16x8*)(Asb + arow * LS + akc) = ar0;
    *(bf16x8*)(Asb + (arow + 64) * LS + akc) = ar1;
    *(bf16x8*)(Bsb + arow * LS + akc) = br0;
    *(bf16x8*)(Bsb + (arow + 64) * LS + akc) = br1;
    __syncthreads();
    if (k0 + 32 < K) {  // prefetch next k-tile; in flight across this tile
      ar0 = *(const bf16x8*)(Ag + k0 + 32);
      ar1 = *(const bf16x8*)(Ag + (size_t)64 * K + k0 + 32);
      br0 = *(const bf16x8*)(Bg + k0 + 32);
      br1 = *(const bf16x8*)(Bg + (size_t)64 * K + k0 + 32);
    }
    bf16x8 af[4], bfr[4];
#pragma unroll
    for (int t = 0; t < 4; ++t)
      af[t] = *(const bf16x8*)(Asb + (mw + t * 16 + l15) * LS + quad * 8);
#pragma unroll
    for (int t = 0; t < 4; ++t)
      bfr[t] = *(const bf16x8*)(Bsb + (nw + t * 16 + l15) * LS + quad * 8);
#pragma unroll
    for (int mt = 0; mt < 4; ++mt)
#pragma unroll
      for (int nt = 0; nt < 4; ++nt)
        acc[mt][nt] = __builtin_amdgcn_mfma_f32_16x16x32_bf16(
            af[mt], bfr[nt], acc[mt][nt], 0, 0, 0);
  }
#pragma unroll
  for (int mt = 0; mt < 4; ++mt)
#pragma unroll
    for (int nt = 0; nt < 4; ++nt) {
      int col = n0 + nw + nt * 16 + l15;
      float bias, cs;
      if constexpr (QKVMODE) {
        bias = (col < 1024) ? b0[col] : ((col < 1088) ? b1[col - 1024] : b2[col - 1088]);
        cs = (col < 1024) ? QSCALE : 1.0f;
      } else {
        bias = b0[col];
        cs = 1.0f;
      }
#pragma unroll
      for (int r = 0; r < 4; ++r) {
        int row = m0 + mw + mt * 16 + quad * 4 + r;
        float v = (acc[mt][nt][r] + bias) * cs;
        if constexpr (sizeof(OutT) == 2)
          C[(size_t)row * N + col] = f2bf(v);
        else
          C[(size_t)row * N + col] = v;
        if constexpr (QKVMODE) {
          if (col >= 1088)  // scatter V^T for flash: Vt[b*64+d][s]
            Vt[((size_t)(row >> 11) * 64 + (col - 1088)) * 2048 + (row & 2047)] =
                f2bf(v);
        }
      }
    }
}

// ---------------- flash attention (MQA, split-K in-block) ----------------
// Grid (S/128, H, B) = 512 blocks, 512 thr = 8 waves: wave = (p = q-group 0..3,
// ks = key-slice 0..1). Each wave: 32 queries x 1024 keys (16 tiles of 64).
// Doubles waves/CU to 16 (the 8-wave/CU grid cap was the R4 plateau).
// S-form (A=Q regs, B=K lds), P round-trip via wave-private LDS (R4-proven),
// single-buffered K/V staged per slice, reg prefetch across compute phase.
// Split-K combine in-block through re-used LDS (softmax is no-max exp2 ->
// partial O and row-sums are additive).
__global__ __launch_bounds__(512, 4) void flash_attn_kernel(
    const unsigned short* __restrict__ QKV,  // [B*S][1152] bf16: Q|K|V
    const unsigned short* __restrict__ Vt,   // [B][64][2048] bf16
    unsigned short* __restrict__ AO) {       // [B*S][1024] bf16
  constexpr int S = 2048, LDQ = 1152;
  constexpr int PK = 72, PP = 72;
  __shared__ unsigned short Ks[2][64 * PK];  // [slice][key][d]
  __shared__ unsigned short Vs[2][64 * PK];  // [slice][d][key]
  __shared__ unsigned short Ps[8][32 * PP];  // per-wave P [q][key]; re-used as Cb
  int tid = threadIdx.x;
  int wid = tid >> 6, lane = tid & 63;
  int l31 = lane & 31, half = lane >> 5;
  int p = wid & 3, ks = wid >> 2;
  int q0 = blockIdx.x * 128, h = blockIdx.y, b = blockIdx.z;

  // Q A-frags: m=q=l31, k(d) = s*16 + half*8 + j
  const unsigned short* Qb =
      QKV + (size_t)(b * S + q0 + p * 32 + l31) * LDQ + h * 64 + half * 8;
  bf16x8 qf[4];
#pragma unroll
  for (int f = 0; f < 4; ++f) qf[f] = *(const bf16x8*)(Qb + f * 16);

  // staging role: 256 threads per slice sl; each stages 2 K + 2 V b128 chunks
  int u = tid & 255, sl = tid >> 8;
  int srow = u >> 2, sc = (u & 3) * 8;  // chunks at cols sc and sc+32
  const unsigned short* Kgb = QKV + ((size_t)b * S) * LDQ + 1024;
  const unsigned short* Vgb = Vt + ((size_t)(b * 64 + srow)) * 2048;

  f32x4 oacc[2][4];  // [d2][reg quad-group] as f32x16 split for clarity
  f32x16 oa0, oa1;
#pragma unroll
  for (int r = 0; r < 16; ++r) { oa0[r] = 0.f; oa1[r] = 0.f; }
  float rs[16];
#pragma unroll
  for (int r = 0; r < 16; ++r) rs[r] = 0.f;

  int kb0 = sl * 1024;
  bf16x8 ka = *(const bf16x8*)(Kgb + (size_t)(kb0 + srow) * LDQ + sc);
  bf16x8 kc = *(const bf16x8*)(Kgb + (size_t)(kb0 + srow) * LDQ + sc + 32);
  bf16x8 va = *(const bf16x8*)(Vgb + kb0 + sc);
  bf16x8 vc = *(const bf16x8*)(Vgb + kb0 + sc + 32);

  unsigned short* Pw = Ps[wid];
  unsigned short* Ksb = Ks[ks];
  unsigned short* Vsb = Vs[ks];

  for (int kt = 0; kt < 16; ++kt) {
    // stage this tile (both slices in parallel across the 512 threads)
    *(bf16x8*)(Ks[sl] + srow * PK + sc) = ka;
    *(bf16x8*)(Ks[sl] + srow * PK + sc + 32) = kc;
    *(bf16x8*)(Vs[sl] + srow * PK + sc) = va;
    *(bf16x8*)(Vs[sl] + srow * PK + sc + 32) = vc;
    __syncthreads();
    if (kt + 1 < 16) {  // prefetch next tile; in flight across compute
      int kbn = sl * 1024 + (kt + 1) * 64;
      ka = *(const bf16x8*)(Kgb + (size_t)(kbn + srow) * LDQ + sc);
      kc = *(const bf16x8*)(Kgb + (size_t)(kbn + srow) * LDQ + sc + 32);
      va = *(const bf16x8*)(Vgb + kbn + sc);
      vc = *(const bf16x8*)(Vgb + kbn + sc + 32);
    }

    // S = Q.K^T : C col=key(n2*32+l31), row=q=(r&3)+8*(r>>2)+4*half
#pragma unroll
    for (int n2 = 0; n2 < 2; ++n2) {
      f32x16 sacc;
#pragma unroll
      for (int i = 0; i < 16; ++i) sacc[i] = 0.f;
#pragma unroll
      for (int s = 0; s < 4; ++s) {
        bf16x8 kf =
            *(const bf16x8*)(Ksb + (n2 * 32 + l31) * PK + s * 16 + half * 8);
        sacc = __builtin_amdgcn_mfma_f32_32x32x16_bf16(qf[s], kf, sacc, 0, 0, 0);
      }
#pragma unroll
      for (int r = 0; r < 16; ++r) {
        float pr = __builtin_amdgcn_exp2f(sacc[r]);
        rs[r] += pr;
        int row = (r & 3) + 8 * (r >> 2) + 4 * half;
        Pw[row * PP + n2 * 32 + l31] = f2bf(pr);
      }
    }

    // O += P.V : A = P from wave-private LDS, B = V^T
    bf16x8 pf[4];
#pragma unroll
    for (int s = 0; s < 4; ++s)
      pf[s] = *(const bf16x8*)(Pw + l31 * PP + s * 16 + half * 8);
#pragma unroll
    for (int s = 0; s < 4; ++s) {
      bf16x8 vf0 = *(const bf16x8*)(Vsb + (l31)*PK + s * 16 + half * 8);
      bf16x8 vf1 = *(const bf16x8*)(Vsb + (32 + l31) * PK + s * 16 + half * 8);
      oa0 = __builtin_amdgcn_mfma_f32_32x32x16_bf16(pf[s], vf0, oa0, 0, 0, 0);
      oa1 = __builtin_amdgcn_mfma_f32_32x32x16_bf16(pf[s], vf1, oa1, 0, 0, 0);
    }
    __syncthreads();  // all LDS (incl. Ps alias region) quiesced each step
  }

  // reduce row-sums over the 32 key-columns (lanes within each half)
#pragma unroll
  for (int r = 0; r < 16; ++r) {
    float t = rs[r];
    t += __shfl_xor(t, 1, 32);
    t += __shfl_xor(t, 2, 32);
    t += __shfl_xor(t, 4, 32);
    t += __shfl_xor(t, 8, 32);
    t += __shfl_xor(t, 16, 32);
    rs[r] = t;
  }

  // split-K combine via LDS (aliases Ps; last loop barrier protects it)
  float* Cb = (float*)Ps;  // [4 groups][32 q][65]: d 0..63 + rs at 64
  if (ks == 1) {
#pragma unroll
    for (int r = 0; r < 16; ++r) {
      int row = (r & 3) + 8 * (r >> 2) + 4 * half;
      Cb[(p * 32 + row) * 65 + l31] = oa0[r];
      Cb[(p * 32 + row) * 65 + 32 + l31] = oa1[r];
      if (l31 == 0) Cb[(p * 32 + row) * 65 + 64] = rs[r];
    }
  }
  __syncthreads();
  if (ks == 0) {
    unsigned short* Ob = AO + (size_t)(b * S + q0 + p * 32) * 1024 + h * 64;
#pragma unroll
    for (int r = 0; r < 16; ++r) {
      int row = (r & 3) + 8 * (r >> 2) + 4 * half;
      float p0 = Cb[(p * 32 + row) * 65 + l31];
      float p1 = Cb[(p * 32 + row) * 65 + 32 + l31];
      float rsu = Cb[(p * 32 + row) * 65 + 64];
      float inv = 1.0f / (rs[r] + rsu);
      Ob[(size_t)row * 1024 + l31] = f2bf((oa0[r] + p0) * inv);
      Ob[(size_t)row * 1024 + 32 + l31] = f2bf((oa1[r] + p1) * inv);
    }
  }
}

extern "C" void kernel_launch(void* const* d_in, const int* in_sizes, int n_in,
                              void* d_out, int out_size, void* d_ws, size_t ws_size,
                              hipStream_t stream) {
  const float* x  = (const float*)d_in[0];
  const float* Wq = (const float*)d_in[1];
  const float* bq = (const float*)d_in[2];
  const float* Wk = (const float*)d_in[3];
  const float* bk = (const float*)d_in[4];
  const float* Wv = (const float*)d_in[5];
  const float* bv = (const float*)d_in[6];
  const float* Wo = (const float*)d_in[7];
  const float* bo = (const float*)d_in[8];
  float* out = (float*)d_out;

  constexpr int B = 2, S = 2048, D = 1024, Dk = 64, H = 16;
  constexpr int M = B * S;          // 4096
  constexpr int NQKV = D + 2 * Dk;  // 1152

  char* ws = (char*)d_ws;
  unsigned short* xb   = (unsigned short*)ws; ws += (size_t)M * D * 2;
  unsigned short* QKVt = (unsigned short*)ws; ws += (size_t)NQKV * D * 2;
  unsigned short* Wot  = (unsigned short*)ws; ws += (size_t)D * D * 2;
  unsigned short* QKV  = (unsigned short*)ws; ws += (size_t)M * NQKV * 2;
  unsigned short* Vtb  = (unsigned short*)ws; ws += (size_t)B * Dk * S * 2;
  unsigned short* AO   = (unsigned short*)ws; ws += (size_t)M * D * 2;

  // 1. prep: convert x (z=4) + transpose/convert 4 weights (z=0..3)
  prep_kernel<<<dim3(32, 32, 5), 256, 0, stream>>>(x, Wq, Wk, Wv, Wo, xb, QKVt, Wot);

  // 2. fused QKV projection (bf16 A, 128x128 tiles = 288 blocks);
  //    epilogue scatters V^T and pre-scales Q by 0.125*log2e
  gemm_bf16_kernel<unsigned short, true><<<dim3(M / 128, NQKV / 128), 256, 0, stream>>>(
      xb, QKVt, bq, bk, bv, QKV, Vtb, M, NQKV, D);

  // 3. attention (split-K in-block: 512 blocks x 8 waves -> 16 waves/CU)
  flash_attn_kernel<<<dim3(S / 128, H, B), 512, 0, stream>>>(QKV, Vtb, AO);

  // 4. output projection (fp32 out, 256 blocks)
  gemm_bf16_kernel<float, false><<<dim3(M / 128, D / 128), 256, 0, stream>>>(
      AO, Wot, bo, nullptr, nullptr, out, nullptr, M, D, D);
}

// Round 9
// 187.668 us; speedup vs baseline: 1.0824x; 1.0433x over previous
//
#include <hip/hip_runtime.h>
#include <hip/hip_bf16.h>

typedef __attribute__((ext_vector_type(8))) short bf16x8;
typedef __attribute__((ext_vector_type(4))) float f32x4;
typedef __attribute__((ext_vector_type(16))) float f32x16;
typedef __attribute__((ext_vector_type(4))) unsigned short ushort4v;

// 0.125 * log2(e): folded into Q so attention probs are exp2(QK) directly
#define QSCALE 0.1803368801111204f

__device__ __forceinline__ unsigned short f2bf(float f) {
  union { float f; unsigned int u; } x; x.f = f;
  unsigned int u = x.u;
  unsigned int r = (u + 0x7fffu + ((u >> 16) & 1u)) >> 16;
  return (unsigned short)r;
}

// single-instruction fp32->bf16 (round-nearest-even via v_cvt_pk_bf16_f32)
__device__ __forceinline__ unsigned short cvt1bf(float a) {
  union { __hip_bfloat162 h; unsigned short s[2]; } c;
  c.h = __float22bfloat162_rn(make_float2(a, a));
  return c.s[0];
}

// ---- fused prep: z<4 transpose+convert weights; z==4 convert x ----
__global__ __launch_bounds__(256) void prep_kernel(
    const float* __restrict__ x,
    const float* __restrict__ Wq, const float* __restrict__ Wk,
    const float* __restrict__ Wv, const float* __restrict__ Wo,
    unsigned short* __restrict__ xb,
    unsigned short* __restrict__ QKVt, unsigned short* __restrict__ Wot) {
  int z = blockIdx.z;
  if (z == 4) {  // x: 4096x1024 fp32 -> bf16
    size_t base = ((size_t)(blockIdx.y * 32 + blockIdx.x)) * 4096 + threadIdx.x * 16;
#pragma unroll
    for (int c = 0; c < 4; ++c) {
      float4 v = *(const float4*)(x + base + c * 4);
      ushort4v o = { f2bf(v.x), f2bf(v.y), f2bf(v.z), f2bf(v.w) };
      *(ushort4v*)(xb + base + c * 4) = o;
    }
    return;
  }
  __shared__ float t[32][33];
  const float* src;
  unsigned short* dst;
  int C, rowoff;
  if (z == 0)      { src = Wq; dst = QKVt; C = 1024; rowoff = 0; }
  else if (z == 1) { src = Wk; dst = QKVt; C = 64;   rowoff = 1024; }
  else if (z == 2) { src = Wv; dst = QKVt; C = 64;   rowoff = 1088; }
  else             { src = Wo; dst = Wot;  C = 1024; rowoff = 0; }
  int c0 = blockIdx.x * 32, r0 = blockIdx.y * 32;
  if (c0 >= C) return;
  int tx = threadIdx.x & 31, ty = threadIdx.x >> 5;
#pragma unroll
  for (int i = 0; i < 32; i += 8)
    t[ty + i][tx] = src[(size_t)(r0 + ty + i) * C + c0 + tx];
  __syncthreads();
#pragma unroll
  for (int i = 0; i < 32; i += 8)
    dst[(size_t)(rowoff + c0 + ty + i) * 1024 + r0 + tx] = f2bf(t[tx][ty + i]);
}

// ------- bf16 MFMA GEMM: C[M][N] = A[M][K] @ Bt[N][K]^T + bias -------
// 128x64 tile (>=2 blocks/CU for these shapes; 128x128 left CUs at 1 block
// = 1 wave/SIMD and ran ~2x slow), BK=32, reg-prefetch + LDS dbuf, ONE
// barrier/iter. 4 waves, each 64x32 (4x2 mfma 16x16x32).
// QKVMODE: per-column bias select + QSCALE on Q cols; V cols scatter V^T.
template <typename OutT, bool QKVMODE>
__global__ __launch_bounds__(256) void gemm_bf16_kernel(
    const unsigned short* __restrict__ A, const unsigned short* __restrict__ Bt,
    const float* __restrict__ b0, const float* __restrict__ b1,
    const float* __restrict__ b2, OutT* __restrict__ C,
    unsigned short* __restrict__ Vt, int M, int N, int K) {
  constexpr int LS = 40;
  __shared__ unsigned short As[2][128 * LS];
  __shared__ unsigned short Bs[2][64 * LS];
  int tid = threadIdx.x;
  int wid = tid >> 6, lane = tid & 63;
  int l15 = lane & 15, quad = lane >> 4;
  int m0 = blockIdx.x * 128, n0 = blockIdx.y * 64;
  int mw = (wid >> 1) * 64, nw = (wid & 1) * 32;
  f32x4 acc[4][2];
#pragma unroll
  for (int i = 0; i < 4; i++)
#pragma unroll
    for (int j = 0; j < 2; j++)
#pragma unroll
      for (int e = 0; e < 4; ++e) acc[i][j][e] = 0.f;

  int arow = tid >> 2, akc = (tid & 3) * 8;  // A: rows arow, arow+64; B: row arow
  const unsigned short* Ag = A + (size_t)(m0 + arow) * K + akc;
  const unsigned short* Bg = Bt + (size_t)(n0 + arow) * K + akc;
  bf16x8 ar0 = *(const bf16x8*)(Ag);
  bf16x8 ar1 = *(const bf16x8*)(Ag + (size_t)64 * K);
  bf16x8 br0 = *(const bf16x8*)(Bg);

  for (int k0 = 0; k0 < K; k0 += 32) {
    unsigned short* Asb = As[(k0 >> 5) & 1];
    unsigned short* Bsb = Bs[(k0 >> 5) & 1];
    *(bf16x8*)(Asb + arow * LS + akc) = ar0;
    *(bf16x8*)(Asb + (arow + 64) * LS + akc) = ar1;
    *(bf16x8*)(Bsb + arow * LS + akc) = br0;
    __syncthreads();
    if (k0 + 32 < K) {  // prefetch next k-tile; in flight across this tile
      ar0 = *(const bf16x8*)(Ag + k0 + 32);
      ar1 = *(const bf16x8*)(Ag + (size_t)64 * K + k0 + 32);
      br0 = *(const bf16x8*)(Bg + k0 + 32);
    }
    bf16x8 af[4], bfr[2];
#pragma unroll
    for (int t = 0; t < 4; ++t)
      af[t] = *(const bf16x8*)(Asb + (mw + t * 16 + l15) * LS + quad * 8);
#pragma unroll
    for (int t = 0; t < 2; ++t)
      bfr[t] = *(const bf16x8*)(Bsb + (nw + t * 16 + l15) * LS + quad * 8);
#pragma unroll
    for (int mt = 0; mt < 4; ++mt)
#pragma unroll
      for (int nt = 0; nt < 2; ++nt)
        acc[mt][nt] = __builtin_amdgcn_mfma_f32_16x16x32_bf16(
            af[mt], bfr[nt], acc[mt][nt], 0, 0, 0);
  }
#pragma unroll
  for (int mt = 0; mt < 4; ++mt)
#pragma unroll
    for (int nt = 0; nt < 2; ++nt) {
      int col = n0 + nw + nt * 16 + l15;
      float bias, cs;
      if constexpr (QKVMODE) {
        bias = (col < 1024) ? b0[col] : ((col < 1088) ? b1[col - 1024] : b2[col - 1088]);
        cs = (col < 1024) ? QSCALE : 1.0f;
      } else {
        bias = b0[col];
        cs = 1.0f;
      }
#pragma unroll
      for (int r = 0; r < 4; ++r) {
        int row = m0 + mw + mt * 16 + quad * 4 + r;
        float v = (acc[mt][nt][r] + bias) * cs;
        if constexpr (sizeof(OutT) == 2)
          C[(size_t)row * N + col] = f2bf(v);
        else
          C[(size_t)row * N + col] = v;
        if constexpr (QKVMODE) {
          if (col >= 1088)  // scatter V^T for flash: Vt[b*64+d][s]
            Vt[((size_t)(row >> 11) * 64 + (col - 1088)) * 2048 + (row & 2047)] =
                f2bf(v);
        }
      }
    }
}

// ---------------- flash attention (MQA, split-K in-block) ----------------
// Grid (S/128, H, B) = 512 blocks, 512 thr = 8 waves: wave = (p = q-group 0..3,
// ks = key-slice 0..1). Each wave: 32 queries x 1024 keys (16 tiles of 64).
// S-form (A=Q regs, B=K lds), P round-trip via wave-private LDS,
// single-buffered K/V staged per slice, reg prefetch across compute phase.
// Split-K combine in-block through re-used LDS (no-max exp2 softmax ->
// partial O and row-sums are additive).
__global__ __launch_bounds__(512, 4) void flash_attn_kernel(
    const unsigned short* __restrict__ QKV,  // [B*S][1152] bf16: Q|K|V
    const unsigned short* __restrict__ Vt,   // [B][64][2048] bf16
    unsigned short* __restrict__ AO) {       // [B*S][1024] bf16
  constexpr int S = 2048, LDQ = 1152;
  constexpr int PK = 72, PP = 72;
  __shared__ unsigned short Ks[2][64 * PK];  // [slice][key][d]
  __shared__ unsigned short Vs[2][64 * PK];  // [slice][d][key]
  __shared__ unsigned short Ps[8][32 * PP];  // per-wave P [q][key]; re-used as Cb
  int tid = threadIdx.x;
  int wid = tid >> 6, lane = tid & 63;
  int l31 = lane & 31, half = lane >> 5;
  int p = wid & 3, ks = wid >> 2;
  int q0 = blockIdx.x * 128, h = blockIdx.y, b = blockIdx.z;

  // Q A-frags: m=q=l31, k(d) = s*16 + half*8 + j
  const unsigned short* Qb =
      QKV + (size_t)(b * S + q0 + p * 32 + l31) * LDQ + h * 64 + half * 8;
  bf16x8 qf[4];
#pragma unroll
  for (int f = 0; f < 4; ++f) qf[f] = *(const bf16x8*)(Qb + f * 16);

  // staging role: 256 threads per slice sl; each stages 2 K + 2 V b128 chunks
  int u = tid & 255, sl = tid >> 8;
  int srow = u >> 2, sc = (u & 3) * 8;  // chunks at cols sc and sc+32
  const unsigned short* Kgb = QKV + ((size_t)b * S) * LDQ + 1024;
  const unsigned short* Vgb = Vt + ((size_t)(b * 64 + srow)) * 2048;

  f32x16 oa0, oa1;
#pragma unroll
  for (int r = 0; r < 16; ++r) { oa0[r] = 0.f; oa1[r] = 0.f; }
  float rs[16];
#pragma unroll
  for (int r = 0; r < 16; ++r) rs[r] = 0.f;

  int kb0 = sl * 1024;
  bf16x8 ka = *(const bf16x8*)(Kgb + (size_t)(kb0 + srow) * LDQ + sc);
  bf16x8 kc = *(const bf16x8*)(Kgb + (size_t)(kb0 + srow) * LDQ + sc + 32);
  bf16x8 va = *(const bf16x8*)(Vgb + kb0 + sc);
  bf16x8 vc = *(const bf16x8*)(Vgb + kb0 + sc + 32);

  unsigned short* Pw = Ps[wid];
  unsigned short* Ksb = Ks[ks];
  unsigned short* Vsb = Vs[ks];

  for (int kt = 0; kt < 16; ++kt) {
    // stage this tile (both slices in parallel across the 512 threads)
    *(bf16x8*)(Ks[sl] + srow * PK + sc) = ka;
    *(bf16x8*)(Ks[sl] + srow * PK + sc + 32) = kc;
    *(bf16x8*)(Vs[sl] + srow * PK + sc) = va;
    *(bf16x8*)(Vs[sl] + srow * PK + sc + 32) = vc;
    __syncthreads();
    if (kt + 1 < 16) {  // prefetch next tile; in flight across compute
      int kbn = sl * 1024 + (kt + 1) * 64;
      ka = *(const bf16x8*)(Kgb + (size_t)(kbn + srow) * LDQ + sc);
      kc = *(const bf16x8*)(Kgb + (size_t)(kbn + srow) * LDQ + sc + 32);
      va = *(const bf16x8*)(Vgb + kbn + sc);
      vc = *(const bf16x8*)(Vgb + kbn + sc + 32);
    }

    // S = Q.K^T : C col=key(n2*32+l31), row=q=(r&3)+8*(r>>2)+4*half
#pragma unroll
    for (int n2 = 0; n2 < 2; ++n2) {
      f32x16 sacc;
#pragma unroll
      for (int i = 0; i < 16; ++i) sacc[i] = 0.f;
#pragma unroll
      for (int s = 0; s < 4; ++s) {
        bf16x8 kf =
            *(const bf16x8*)(Ksb + (n2 * 32 + l31) * PK + s * 16 + half * 8);
        sacc = __builtin_amdgcn_mfma_f32_32x32x16_bf16(qf[s], kf, sacc, 0, 0, 0);
      }
#pragma unroll
      for (int r = 0; r < 16; ++r) {
        float pr = __builtin_amdgcn_exp2f(sacc[r]);
        rs[r] += pr;
        int row = (r & 3) + 8 * (r >> 2) + 4 * half;
        Pw[row * PP + n2 * 32 + l31] = cvt1bf(pr);  // 1-instr cvt, b16 store
      }
    }

    // O += P.V : A = P from wave-private LDS, B = V^T
    bf16x8 pf[4];
#pragma unroll
    for (int s = 0; s < 4; ++s)
      pf[s] = *(const bf16x8*)(Pw + l31 * PP + s * 16 + half * 8);
#pragma unroll
    for (int s = 0; s < 4; ++s) {
      bf16x8 vf0 = *(const bf16x8*)(Vsb + (l31)*PK + s * 16 + half * 8);
      bf16x8 vf1 = *(const bf16x8*)(Vsb + (32 + l31) * PK + s * 16 + half * 8);
      oa0 = __builtin_amdgcn_mfma_f32_32x32x16_bf16(pf[s], vf0, oa0, 0, 0, 0);
      oa1 = __builtin_amdgcn_mfma_f32_32x32x16_bf16(pf[s], vf1, oa1, 0, 0, 0);
    }
    __syncthreads();  // all LDS (incl. Ps alias region) quiesced each step
  }

  // reduce row-sums over the 32 key-columns (lanes within each half)
#pragma unroll
  for (int r = 0; r < 16; ++r) {
    float t = rs[r];
    t += __shfl_xor(t, 1, 32);
    t += __shfl_xor(t, 2, 32);
    t += __shfl_xor(t, 4, 32);
    t += __shfl_xor(t, 8, 32);
    t += __shfl_xor(t, 16, 32);
    rs[r] = t;
  }

  // split-K combine via LDS (aliases Ps; last loop barrier protects it)
  float* Cb = (float*)Ps;  // [4 groups][32 q][65]: d 0..63 + rs at 64
  if (ks == 1) {
#pragma unroll
    for (int r = 0; r < 16; ++r) {
      int row = (r & 3) + 8 * (r >> 2) + 4 * half;
      Cb[(p * 32 + row) * 65 + l31] = oa0[r];
      Cb[(p * 32 + row) * 65 + 32 + l31] = oa1[r];
      if (l31 == 0) Cb[(p * 32 + row) * 65 + 64] = rs[r];
    }
  }
  __syncthreads();
  if (ks == 0) {
    unsigned short* Ob = AO + (size_t)(b * S + q0 + p * 32) * 1024 + h * 64;
#pragma unroll
    for (int r = 0; r < 16; ++r) {
      int row = (r & 3) + 8 * (r >> 2) + 4 * half;
      float p0 = Cb[(p * 32 + row) * 65 + l31];
      float p1 = Cb[(p * 32 + row) * 65 + 32 + l31];
      float rsu = Cb[(p * 32 + row) * 65 + 64];
      float inv = 1.0f / (rs[r] + rsu);
      Ob[(size_t)row * 1024 + l31] = f2bf((oa0[r] + p0) * inv);
      Ob[(size_t)row * 1024 + 32 + l31] = f2bf((oa1[r] + p1) * inv);
    }
  }
}

extern "C" void kernel_launch(void* const* d_in, const int* in_sizes, int n_in,
                              void* d_out, int out_size, void* d_ws, size_t ws_size,
                              hipStream_t stream) {
  const float* x  = (const float*)d_in[0];
  const float* Wq = (const float*)d_in[1];
  const float* bq = (const float*)d_in[2];
  const float* Wk = (const float*)d_in[3];
  const float* bk = (const float*)d_in[4];
  const float* Wv = (const float*)d_in[5];
  const float* bv = (const float*)d_in[6];
  const float* Wo = (const float*)d_in[7];
  const float* bo = (const float*)d_in[8];
  float* out = (float*)d_out;

  constexpr int B = 2, S = 2048, D = 1024, Dk = 64, H = 16;
  constexpr int M = B * S;          // 4096
  constexpr int NQKV = D + 2 * Dk;  // 1152

  char* ws = (char*)d_ws;
  unsigned short* xb   = (unsigned short*)ws; ws += (size_t)M * D * 2;
  unsigned short* QKVt = (unsigned short*)ws; ws += (size_t)NQKV * D * 2;
  unsigned short* Wot  = (unsigned short*)ws; ws += (size_t)D * D * 2;
  unsigned short* QKV  = (unsigned short*)ws; ws += (size_t)M * NQKV * 2;
  unsigned short* Vtb  = (unsigned short*)ws; ws += (size_t)B * Dk * S * 2;
  unsigned short* AO   = (unsigned short*)ws; ws += (size_t)M * D * 2;

  // 1. prep: convert x (z=4) + transpose/convert 4 weights (z=0..3)
  prep_kernel<<<dim3(32, 32, 5), 256, 0, stream>>>(x, Wq, Wk, Wv, Wo, xb, QKVt, Wot);

  // 2. fused QKV projection (128x64 tiles = 576 blocks -> 2.25 blocks/CU);
  //    epilogue scatters V^T and pre-scales Q by 0.125*log2e
  gemm_bf16_kernel<unsigned short, true><<<dim3(M / 128, NQKV / 64), 256, 0, stream>>>(
      xb, QKVt, bq, bk, bv, QKV, Vtb, M, NQKV, D);

  // 3. attention (split-K in-block: 512 blocks x 8 waves)
  flash_attn_kernel<<<dim3(S / 128, H, B), 512, 0, stream>>>(QKV, Vtb, AO);

  // 4. output projection (fp32 out, 128x64 tiles = 512 blocks -> 2 blocks/CU)
  gemm_bf16_kernel<float, false><<<dim3(M / 128, D / 64), 256, 0, stream>>>(
      AO, Wot, bo, nullptr, nullptr, out, nullptr, M, D, D);
}